// Round 1
// baseline (101.744 us; speedup 1.0000x reference)
//
#include <hip/hip_runtime.h>
#include <math.h>

#define NPTS 2048
#define IMG_H 512
#define IMG_W 512
#define PSTRIDE 12   // ux,uy,A,B,C, r,g,b, a, depth, cullth, pad
#define TILE 16

// ---------------------------------------------------------------------------
// Kernel 1: transform + project each point, store unsorted point records.
// ---------------------------------------------------------------------------
__global__ __launch_bounds__(256) void gs_setup(
    const float* __restrict__ pc,   // (N,3)
    const float* __restrict__ col,  // (N,3)
    const float* __restrict__ alp,  // (N,)
    const float* __restrict__ con,  // (N,3)
    const float* __restrict__ q,    // (4,)
    const float* __restrict__ t,    // (3,)
    const float* __restrict__ K,    // (3,3)
    float* __restrict__ depth_un,
    float* __restrict__ data_un) {
  int i = blockIdx.x * blockDim.x + threadIdx.x;
  if (i >= NPTS) return;
  float qx = q[0], qy = q[1], qz = q[2], qw = q[3];
  float r00 = 1.f - 2.f * (qy * qy + qz * qz), r01 = 2.f * (qx * qy - qz * qw),
        r02 = 2.f * (qx * qz + qy * qw);
  float r10 = 2.f * (qx * qy + qz * qw), r11 = 1.f - 2.f * (qx * qx + qz * qz),
        r12 = 2.f * (qy * qz - qx * qw);
  float r20 = 2.f * (qx * qz - qy * qw), r21 = 2.f * (qy * qz + qx * qw),
        r22 = 1.f - 2.f * (qx * qx + qy * qy);
  float x = pc[i * 3 + 0], y = pc[i * 3 + 1], z = pc[i * 3 + 2];
  float X = r00 * x + r01 * y + r02 * z + t[0];
  float Y = r10 * x + r11 * y + r12 * z + t[1];
  float Z = r20 * x + r21 * y + r22 * z + t[2];
  float fx = K[0], cx = K[2], fy = K[4], cy = K[5];
  float inv = 1.0f / (Z + 1e-6f);
  float ux = (fx * X + cx * Z) * inv;
  float uy = (fy * Y + cy * Z) * inv;
  float a = alp[i];
  float* d = data_un + (size_t)i * PSTRIDE;
  d[0] = ux;
  d[1] = uy;
  d[2] = con[i * 3 + 0];
  d[3] = con[i * 3 + 1];
  d[4] = con[i * 3 + 2];
  d[5] = col[i * 3 + 0];
  d[6] = col[i * 3 + 1];
  d[7] = col[i * 3 + 2];
  d[8] = a;
  d[9] = Z;
  // keep point for a tile iff min_{tile} quadform <= 2*ln(255*a)
  d[10] = 2.0f * logf(255.0f * a);
  d[11] = 0.0f;
  depth_un[i] = Z;
}

// ---------------------------------------------------------------------------
// Kernel 2: stable rank sort by depth (matches jnp.argsort), scatter records.
// ---------------------------------------------------------------------------
__global__ __launch_bounds__(256) void gs_sort(
    const float* __restrict__ depth_un,
    const float* __restrict__ data_un,
    float* __restrict__ sorted) {
  __shared__ float sd[NPTS];
  int tid = threadIdx.x;
  for (int j = tid; j < NPTS; j += blockDim.x) sd[j] = depth_un[j];
  __syncthreads();
  int i = blockIdx.x * blockDim.x + tid;
  if (i >= NPTS) return;
  float di = sd[i];
  int rank = 0;
  for (int j = 0; j < NPTS; j++) {
    float dj = sd[j];
    rank += (dj < di) || (dj == di && j < i);
  }
  const float* s = data_un + (size_t)i * PSTRIDE;
  float* d = sorted + (size_t)rank * PSTRIDE;
  for (int c = 0; c < PSTRIDE; c++) d[c] = s[c];
}

// ---------------------------------------------------------------------------
// Kernel 3: tiled rasterizer. One 256-thread block per 16x16 pixel tile.
// Chunks of 256 sorted points: block-wide ordered compaction of surviving
// points into LDS, then per-pixel front-to-back compositing.
// ---------------------------------------------------------------------------
__global__ __launch_bounds__(256) void gs_raster(
    const float* __restrict__ sp, float* __restrict__ out) {
  __shared__ float s_pts[256 * PSTRIDE];
  __shared__ int s_wsum[4];

  int tid = threadIdx.x;
  int lane = tid & 63, wave = tid >> 6;
  int tilex = (blockIdx.x % (IMG_W / TILE)) * TILE;
  int tiley = (blockIdx.x / (IMG_W / TILE)) * TILE;
  int lx = tid % TILE, ly = tid / TILE;
  float px = tilex + lx + 0.5f, py = tiley + ly + 0.5f;
  float tx0 = tilex + 0.5f, tx1 = tilex + TILE - 0.5f;
  float ty0 = tiley + 0.5f, ty1 = tiley + TILE - 0.5f;

  float T = 1.0f, accr = 0.f, accg = 0.f, accb = 0.f, accd = 0.f;
  bool done = false;

  for (int base = 0; base < NPTS; base += 256) {
    int i = base + tid;
    const float4* g4 = (const float4*)(sp + (size_t)i * PSTRIDE);
    float4 v0 = g4[0];
    float4 v1 = g4[1];
    float4 v2 = g4[2];
    // conservative tile cull: quadform >= (A-|B|)dx^2 + (C-|B|)dy^2
    float ux = v0.x, uy = v0.y, A = v0.z, B = v0.w, C = v1.x;
    float absB = fabsf(B);
    float dxm = fmaxf(0.0f, fmaxf(tx0 - ux, ux - tx1));
    float dym = fmaxf(0.0f, fmaxf(ty0 - uy, uy - ty1));
    float bound =
        fmaxf(A - absB, 0.0f) * dxm * dxm + fmaxf(C - absB, 0.0f) * dym * dym;
    bool pred = bound <= v2.z + 1e-3f;  // v2.z = 2*ln(255*a); slack -> keep

    unsigned long long m = __ballot(pred);
    int my_in_wave = __popcll(m & ((1ull << lane) - 1ull));
    if (lane == 0) s_wsum[wave] = __popcll(m);
    __syncthreads();  // (1) s_wsum ready; prev-iter s_pts readers finished
    int off = 0;
    for (int w = 0; w < wave; w++) off += s_wsum[w];
    int total = s_wsum[0] + s_wsum[1] + s_wsum[2] + s_wsum[3];
    if (pred) {
      float* d = s_pts + (size_t)(off + my_in_wave) * PSTRIDE;
      ((float4*)d)[0] = v0;
      ((float4*)d)[1] = v1;
      ((float4*)d)[2] = v2;
    }
    __syncthreads();  // (2) s_pts compacted

    if (!done) {
      for (int k = 0; k < total; k++) {
        const float4* p4 = (const float4*)(s_pts + (size_t)k * PSTRIDE);
        float4 w0 = p4[0];
        float4 w1 = p4[1];
        float4 w2 = p4[2];
        float dx = px - w0.x, dy = py - w0.y;
        float pw = -0.5f * (w0.z * dx * dx + 2.0f * w0.w * dx * dy +
                            w1.x * dy * dy);
        float g = __expf(fminf(pw, 0.0f));
        float prod = g * w2.x;  // * alpha_i
        if (prod >= (1.0f / 255.0f)) {
          float alpha = fminf(prod, 0.99f);
          float w = T * alpha;
          accr += w * w1.y;
          accg += w * w1.z;
          accb += w * w1.w;
          accd += w * w2.y;  // depth
          T *= (1.0f - alpha);
          if (T < 1e-4f) {
            done = true;
            break;
          }
        }
      }
    }
    // (3) barrier; block-wide early exit when every pixel saturated
    if (__syncthreads_count(done ? 1 : 0) == 256) break;
  }

  int o = ((tiley + ly) * IMG_W + (tilex + lx)) * 5;
  out[o + 0] = accr;
  out[o + 1] = accg;
  out[o + 2] = accb;
  out[o + 3] = accd;
  out[o + 4] = 1.0f - T;
}

extern "C" void kernel_launch(void* const* d_in, const int* in_sizes, int n_in,
                              void* d_out, int out_size, void* d_ws,
                              size_t ws_size, hipStream_t stream) {
  const float* pc = (const float*)d_in[0];
  const float* col = (const float*)d_in[1];
  const float* alp = (const float*)d_in[2];
  const float* con = (const float*)d_in[3];
  const float* q = (const float*)d_in[4];
  const float* t = (const float*)d_in[5];
  const float* K = (const float*)d_in[6];
  float* out = (float*)d_out;

  float* ws = (float*)d_ws;
  float* depth_un = ws;                       // 2048
  float* data_un = ws + NPTS;                 // 2048*12
  float* sorted = ws + NPTS + NPTS * PSTRIDE; // 2048*12

  gs_setup<<<NPTS / 256, 256, 0, stream>>>(pc, col, alp, con, q, t, K,
                                           depth_un, data_un);
  gs_sort<<<NPTS / 256, 256, 0, stream>>>(depth_un, data_un, sorted);
  gs_raster<<<(IMG_H / TILE) * (IMG_W / TILE), 256, 0, stream>>>(sorted, out);
}

// Round 2
// 65.054 us; speedup vs baseline: 1.5640x; 1.5640x over previous
//
#include <hip/hip_runtime.h>
#include <math.h>

#define NPTS 2048
#define IMG_H 512
#define IMG_W 512
#define PSTRIDE 12   // ux,uy,A,B,C, r,g,b, a, depth, cullth, pad
#define TILE 16

// ---------------------------------------------------------------------------
// Kernel 1: transform + project each point, store unsorted point records.
// ---------------------------------------------------------------------------
__global__ __launch_bounds__(256) void gs_setup(
    const float* __restrict__ pc,   // (N,3)
    const float* __restrict__ col,  // (N,3)
    const float* __restrict__ alp,  // (N,)
    const float* __restrict__ con,  // (N,3)
    const float* __restrict__ q,    // (4,)
    const float* __restrict__ t,    // (3,)
    const float* __restrict__ K,    // (3,3)
    float* __restrict__ depth_un,
    float* __restrict__ data_un) {
  int i = blockIdx.x * blockDim.x + threadIdx.x;
  if (i >= NPTS) return;
  float qx = q[0], qy = q[1], qz = q[2], qw = q[3];
  float r00 = 1.f - 2.f * (qy * qy + qz * qz), r01 = 2.f * (qx * qy - qz * qw),
        r02 = 2.f * (qx * qz + qy * qw);
  float r10 = 2.f * (qx * qy + qz * qw), r11 = 1.f - 2.f * (qx * qx + qz * qz),
        r12 = 2.f * (qy * qz - qx * qw);
  float r20 = 2.f * (qx * qz - qy * qw), r21 = 2.f * (qy * qz + qx * qw),
        r22 = 1.f - 2.f * (qx * qx + qy * qy);
  float x = pc[i * 3 + 0], y = pc[i * 3 + 1], z = pc[i * 3 + 2];
  float X = r00 * x + r01 * y + r02 * z + t[0];
  float Y = r10 * x + r11 * y + r12 * z + t[1];
  float Z = r20 * x + r21 * y + r22 * z + t[2];
  float fx = K[0], cx = K[2], fy = K[4], cy = K[5];
  float inv = 1.0f / (Z + 1e-6f);
  float ux = (fx * X + cx * Z) * inv;
  float uy = (fy * Y + cy * Z) * inv;
  float a = alp[i];
  float* d = data_un + (size_t)i * PSTRIDE;
  d[0] = ux;
  d[1] = uy;
  d[2] = con[i * 3 + 0];
  d[3] = con[i * 3 + 1];
  d[4] = con[i * 3 + 2];
  d[5] = col[i * 3 + 0];
  d[6] = col[i * 3 + 1];
  d[7] = col[i * 3 + 2];
  d[8] = a;
  d[9] = Z;
  // keep point for a tile iff min_{tile} quadform <= 2*ln(255*a)
  d[10] = 2.0f * logf(255.0f * a);
  d[11] = 0.0f;
  depth_un[i] = Z;
}

// ---------------------------------------------------------------------------
// Kernel 2: stable rank sort by depth (matches jnp.argsort), scatter records.
// 4 threads cooperate per point: each counts 1/4 of the comparisons via
// float4 LDS reads (interleaved 16B chunks -> conflict-free), butterfly
// reduce, then each of the 4 writes a 3-float slice of the record.
// Grid: 32 blocks x 256 threads = 4*NPTS.
// ---------------------------------------------------------------------------
__global__ __launch_bounds__(256) void gs_sort(
    const float* __restrict__ depth_un,
    const float* __restrict__ data_un,
    float* __restrict__ sorted) {
  __shared__ float sd[NPTS];
  int tid = threadIdx.x;
  for (int j = tid; j < NPTS; j += 256) sd[j] = depth_un[j];
  __syncthreads();
  int g = (blockIdx.x * 256 + tid) >> 2;  // point index
  int sub = tid & 3;                      // j-range quarter
  float di = sd[g];
  int rank = 0;
  const float4* sd4 = (const float4*)sd;
#pragma unroll 4
  for (int jj = 0; jj < NPTS / 16; jj++) {
    int j4 = jj * 4 + sub;  // interleaved float4 index -> consecutive banks
    float4 dv = sd4[j4];
    int jb = j4 * 4;
    rank += (dv.x < di) || (dv.x == di && jb + 0 < g);
    rank += (dv.y < di) || (dv.y == di && jb + 1 < g);
    rank += (dv.z < di) || (dv.z == di && jb + 2 < g);
    rank += (dv.w < di) || (dv.w == di && jb + 3 < g);
  }
  rank += __shfl_xor(rank, 1);
  rank += __shfl_xor(rank, 2);  // all 4 sub-lanes now hold the full rank
  const float* s = data_un + (size_t)g * PSTRIDE;
  float* d = sorted + (size_t)rank * PSTRIDE;
#pragma unroll
  for (int c = 0; c < 3; c++) d[sub * 3 + c] = s[sub * 3 + c];
}

// ---------------------------------------------------------------------------
// Kernel 3: tiled rasterizer. One 256-thread block per 16x16 pixel tile.
// Chunks of 256 sorted points: block-wide ordered compaction of surviving
// points into LDS, then per-pixel front-to-back compositing.
// ---------------------------------------------------------------------------
__global__ __launch_bounds__(256) void gs_raster(
    const float* __restrict__ sp, float* __restrict__ out) {
  __shared__ float s_pts[256 * PSTRIDE];
  __shared__ int s_wsum[4];

  int tid = threadIdx.x;
  int lane = tid & 63, wave = tid >> 6;
  int tilex = (blockIdx.x % (IMG_W / TILE)) * TILE;
  int tiley = (blockIdx.x / (IMG_W / TILE)) * TILE;
  int lx = tid % TILE, ly = tid / TILE;
  float px = tilex + lx + 0.5f, py = tiley + ly + 0.5f;
  float tx0 = tilex + 0.5f, tx1 = tilex + TILE - 0.5f;
  float ty0 = tiley + 0.5f, ty1 = tiley + TILE - 0.5f;

  float T = 1.0f, accr = 0.f, accg = 0.f, accb = 0.f, accd = 0.f;
  bool done = false;

  for (int base = 0; base < NPTS; base += 256) {
    int i = base + tid;
    const float4* g4 = (const float4*)(sp + (size_t)i * PSTRIDE);
    float4 v0 = g4[0];
    float4 v1 = g4[1];
    float4 v2 = g4[2];
    // conservative tile cull: quadform >= (A-|B|)dx^2 + (C-|B|)dy^2
    float ux = v0.x, uy = v0.y, A = v0.z, B = v0.w, C = v1.x;
    float absB = fabsf(B);
    float dxm = fmaxf(0.0f, fmaxf(tx0 - ux, ux - tx1));
    float dym = fmaxf(0.0f, fmaxf(ty0 - uy, uy - ty1));
    float bound =
        fmaxf(A - absB, 0.0f) * dxm * dxm + fmaxf(C - absB, 0.0f) * dym * dym;
    bool pred = bound <= v2.z + 1e-3f;  // v2.z = 2*ln(255*a); slack -> keep

    unsigned long long m = __ballot(pred);
    int my_in_wave = __popcll(m & ((1ull << lane) - 1ull));
    if (lane == 0) s_wsum[wave] = __popcll(m);
    __syncthreads();  // (1) s_wsum ready; prev-iter s_pts readers finished
    int off = 0;
    for (int w = 0; w < wave; w++) off += s_wsum[w];
    int total = s_wsum[0] + s_wsum[1] + s_wsum[2] + s_wsum[3];
    if (pred) {
      float* d = s_pts + (size_t)(off + my_in_wave) * PSTRIDE;
      ((float4*)d)[0] = v0;
      ((float4*)d)[1] = v1;
      ((float4*)d)[2] = v2;
    }
    __syncthreads();  // (2) s_pts compacted

    if (!done) {
      for (int k = 0; k < total; k++) {
        const float4* p4 = (const float4*)(s_pts + (size_t)k * PSTRIDE);
        float4 w0 = p4[0];
        float4 w1 = p4[1];
        float4 w2 = p4[2];
        float dx = px - w0.x, dy = py - w0.y;
        float pw = -0.5f * (w0.z * dx * dx + 2.0f * w0.w * dx * dy +
                            w1.x * dy * dy);
        float g = __expf(fminf(pw, 0.0f));
        float prod = g * w2.x;  // * alpha_i
        if (prod >= (1.0f / 255.0f)) {
          float alpha = fminf(prod, 0.99f);
          float w = T * alpha;
          accr += w * w1.y;
          accg += w * w1.z;
          accb += w * w1.w;
          accd += w * w2.y;  // depth
          T *= (1.0f - alpha);
          if (T < 1e-4f) {
            done = true;
            break;
          }
        }
      }
    }
    // (3) barrier; block-wide early exit when every pixel saturated
    if (__syncthreads_count(done ? 1 : 0) == 256) break;
  }

  int o = ((tiley + ly) * IMG_W + (tilex + lx)) * 5;
  out[o + 0] = accr;
  out[o + 1] = accg;
  out[o + 2] = accb;
  out[o + 3] = accd;
  out[o + 4] = 1.0f - T;
}

extern "C" void kernel_launch(void* const* d_in, const int* in_sizes, int n_in,
                              void* d_out, int out_size, void* d_ws,
                              size_t ws_size, hipStream_t stream) {
  const float* pc = (const float*)d_in[0];
  const float* col = (const float*)d_in[1];
  const float* alp = (const float*)d_in[2];
  const float* con = (const float*)d_in[3];
  const float* q = (const float*)d_in[4];
  const float* t = (const float*)d_in[5];
  const float* K = (const float*)d_in[6];
  float* out = (float*)d_out;

  float* ws = (float*)d_ws;
  float* depth_un = ws;                       // 2048
  float* data_un = ws + NPTS;                 // 2048*12
  float* sorted = ws + NPTS + NPTS * PSTRIDE; // 2048*12

  gs_setup<<<NPTS / 256, 256, 0, stream>>>(pc, col, alp, con, q, t, K,
                                           depth_un, data_un);
  gs_sort<<<(NPTS * 4) / 256, 256, 0, stream>>>(depth_un, data_un, sorted);
  gs_raster<<<(IMG_H / TILE) * (IMG_W / TILE), 256, 0, stream>>>(sorted, out);
}

// Round 3
// 21.179 us; speedup vs baseline: 4.8041x; 3.0717x over previous
//
#include <hip/hip_runtime.h>
#include <math.h>

#define NPTS 2048
#define IMG_H 512
#define IMG_W 512
#define PSTRIDE 12  // v0=(ux,uy,A,B) v1=(C,th,a,depth) v2=(r,g,b,pad)
#define TILE 16
#define CAP 768     // survivor capacity in LDS (expected ~30/tile)

// ---------------------------------------------------------------------------
// Kernel 1: fused setup + stable rank sort. 256 blocks x 256 threads,
// 32 threads per point. Each block recomputes all 2048 depths into LDS
// (cheaper than a global round-trip), then each 32-thread group ranks its
// point; sub==0 computes the full record and scatters it at `rank`.
// ---------------------------------------------------------------------------
__global__ __launch_bounds__(256) void gs_sortsetup(
    const float* __restrict__ pc,   // (N,3)
    const float* __restrict__ col,  // (N,3)
    const float* __restrict__ alp,  // (N,)
    const float* __restrict__ con,  // (N,3)
    const float* __restrict__ q,    // (4,)
    const float* __restrict__ t,    // (3,)
    const float* __restrict__ K,    // (3,3)
    float* __restrict__ sorted) {
  __shared__ float sd[NPTS];
  int tid = threadIdx.x;
  float qx = q[0], qy = q[1], qz = q[2], qw = q[3];
  float r20 = 2.f * (qx * qz - qy * qw), r21 = 2.f * (qy * qz + qx * qw),
        r22 = 1.f - 2.f * (qx * qx + qy * qy);
  float t2 = t[2];
  for (int j = tid; j < NPTS; j += 256) {
    float x = pc[j * 3 + 0], y = pc[j * 3 + 1], z = pc[j * 3 + 2];
    sd[j] = r20 * x + r21 * y + r22 * z + t2;
  }
  __syncthreads();

  int g = (blockIdx.x * 256 + tid) >> 5;  // point index (8 per block)
  int sub = tid & 31;                     // j-range slice
  float di = sd[g];
  int rank = 0;
  const float4* sd4 = (const float4*)sd;
#pragma unroll
  for (int jj = 0; jj < NPTS / (32 * 4); jj++) {  // 16 iters of float4
    int j4 = jj * 32 + sub;
    float4 dv = sd4[j4];
    int jb = j4 * 4;
    rank += (dv.x < di) || (dv.x == di && jb + 0 < g);
    rank += (dv.y < di) || (dv.y == di && jb + 1 < g);
    rank += (dv.z < di) || (dv.z == di && jb + 2 < g);
    rank += (dv.w < di) || (dv.w == di && jb + 3 < g);
  }
  rank += __shfl_xor(rank, 1);
  rank += __shfl_xor(rank, 2);
  rank += __shfl_xor(rank, 4);
  rank += __shfl_xor(rank, 8);
  rank += __shfl_xor(rank, 16);  // all 32 sub-lanes hold the full rank

  if (sub == 0) {
    float r00 = 1.f - 2.f * (qy * qy + qz * qz),
          r01 = 2.f * (qx * qy - qz * qw), r02 = 2.f * (qx * qz + qy * qw);
    float r10 = 2.f * (qx * qy + qz * qw),
          r11 = 1.f - 2.f * (qx * qx + qz * qz),
          r12 = 2.f * (qy * qz - qx * qw);
    float x = pc[g * 3 + 0], y = pc[g * 3 + 1], z = pc[g * 3 + 2];
    float X = r00 * x + r01 * y + r02 * z + t[0];
    float Y = r10 * x + r11 * y + r12 * z + t[1];
    float Z = di;  // depth already computed
    float fx = K[0], cx = K[2], fy = K[4], cy = K[5];
    float inv = 1.0f / (Z + 1e-6f);
    float ux = (fx * X + cx * Z) * inv;
    float uy = (fy * Y + cy * Z) * inv;
    float a = alp[g];
    float4 w0 = {ux, uy, con[g * 3 + 0], con[g * 3 + 1]};
    float4 w1 = {con[g * 3 + 2], 2.0f * logf(255.0f * a), a, Z};
    float4 w2 = {col[g * 3 + 0], col[g * 3 + 1], col[g * 3 + 2], 0.0f};
    float4* d = (float4*)(sorted + (size_t)rank * PSTRIDE);
    d[0] = w0;
    d[1] = w1;
    d[2] = w2;
  }
}

// ---------------------------------------------------------------------------
// Kernel 2: tiled rasterizer, single cull pass + single composite pass.
// One 256-thread block per 16x16 tile. All 8 chunks' cull loads are issued
// up-front (independent -> pipelined), one barrier, ordered compaction of
// all survivors into LDS, one barrier, one composite loop. Exact per-chunk
// fallback if survivors exceed CAP.
// ---------------------------------------------------------------------------
__global__ __launch_bounds__(256, 4) void gs_raster(
    const float* __restrict__ sp, float* __restrict__ out) {
  __shared__ float s_pts[CAP * PSTRIDE];
  __shared__ int s_cnt[32];  // [chunk][wave]

  int tid = threadIdx.x;
  int lane = tid & 63, wave = tid >> 6;
  int tilex = (blockIdx.x % (IMG_W / TILE)) * TILE;
  int tiley = (blockIdx.x / (IMG_W / TILE)) * TILE;
  int lx = tid % TILE, ly = tid / TILE;
  float px = tilex + lx + 0.5f, py = tiley + ly + 0.5f;
  float tx0 = tilex + 0.5f, tx1 = tilex + TILE - 0.5f;
  float ty0 = tiley + 0.5f, ty1 = tiley + TILE - 0.5f;

  float4 v0[8], v1[8];
#pragma unroll
  for (int c = 0; c < 8; c++) {
    const float4* g4 = (const float4*)(sp + (size_t)(c * 256 + tid) * PSTRIDE);
    v0[c] = g4[0];
    v1[c] = g4[1];
  }

  int miw[8];
  unsigned pmask = 0;
#pragma unroll
  for (int c = 0; c < 8; c++) {
    float ux = v0[c].x, uy = v0[c].y, A = v0[c].z, B = v0[c].w;
    float C = v1[c].x, th = v1[c].y;
    float absB = fabsf(B);
    float dxm = fmaxf(0.0f, fmaxf(tx0 - ux, ux - tx1));
    float dym = fmaxf(0.0f, fmaxf(ty0 - uy, uy - ty1));
    float bound =
        fmaxf(A - absB, 0.0f) * dxm * dxm + fmaxf(C - absB, 0.0f) * dym * dym;
    bool pred = bound <= th + 1e-3f;
    unsigned long long m = __ballot(pred);
    miw[c] = __popcll(m & ((1ull << lane) - 1ull));
    if (lane == 0) s_cnt[c * 4 + wave] = (int)__popcll(m);
    pmask |= (unsigned)pred << c;
  }
  __syncthreads();

  // prefix sums over the 32 (chunk-major) counts, broadcast LDS reads
  int start[8], ctot[8], total = 0;
  {
    int run = 0;
#pragma unroll
    for (int c = 0; c < 8; c++) {
      int s0 = s_cnt[c * 4 + 0], s1 = s_cnt[c * 4 + 1];
      int s2 = s_cnt[c * 4 + 2], s3 = s_cnt[c * 4 + 3];
      start[c] = run + (wave > 0 ? s0 : 0) + (wave > 1 ? s1 : 0) +
                 (wave > 2 ? s2 : 0);
      ctot[c] = s0 + s1 + s2 + s3;
      run += ctot[c];
    }
    total = run;
  }

  float T = 1.0f, accr = 0.f, accg = 0.f, accb = 0.f, accd = 0.f;

#define COMPOSITE(k)                                                       \
  {                                                                        \
    const float4* p4 = (const float4*)(s_pts + (size_t)(k)*PSTRIDE);       \
    float4 w0 = p4[0], w1 = p4[1], w2 = p4[2];                             \
    float dx = px - w0.x, dy = py - w0.y;                                  \
    float pw =                                                             \
        -0.5f * (w0.z * dx * dx + 2.0f * w0.w * dx * dy + w1.x * dy * dy); \
    float gg = __expf(fminf(pw, 0.0f));                                    \
    float prod = gg * w1.z;                                                \
    if (prod >= (1.0f / 255.0f)) {                                         \
      float al = fminf(prod, 0.99f);                                       \
      float w = T * al;                                                    \
      accr += w * w2.x;                                                    \
      accg += w * w2.y;                                                    \
      accb += w * w2.z;                                                    \
      accd += w * w1.w;                                                    \
      T *= (1.0f - al);                                                    \
    }                                                                      \
  }

  if (total <= CAP) {
    // fast path: compact all survivors at once
#pragma unroll
    for (int c = 0; c < 8; c++) {
      if ((pmask >> c) & 1) {
        int i = c * 256 + tid;
        float4 v2 = ((const float4*)(sp + (size_t)i * PSTRIDE))[2];
        float4* d = (float4*)(s_pts + (size_t)(start[c] + miw[c]) * PSTRIDE);
        d[0] = v0[c];
        d[1] = v1[c];
        d[2] = v2;
      }
    }
    __syncthreads();
    for (int k = 0; k < total; k++) {
      COMPOSITE(k);
      if (T < 1e-4f) break;
    }
  } else {
    // exact fallback: chunk at a time (each chunk <= 256 <= CAP)
    int chunkstart = 0;
#pragma unroll
    for (int c = 0; c < 8; c++) {
      __syncthreads();  // previous chunk's readers done before overwrite
      if ((pmask >> c) & 1) {
        int i = c * 256 + tid;
        float4 v2 = ((const float4*)(sp + (size_t)i * PSTRIDE))[2];
        float4* d = (float4*)(s_pts +
                              (size_t)(start[c] - chunkstart + miw[c]) *
                                  PSTRIDE);
        d[0] = v0[c];
        d[1] = v1[c];
        d[2] = v2;
      }
      __syncthreads();
      if (T >= 1e-4f) {
        for (int k = 0; k < ctot[c]; k++) {
          COMPOSITE(k);
          if (T < 1e-4f) break;
        }
      }
      chunkstart += ctot[c];
    }
  }
#undef COMPOSITE

  int o = ((tiley + ly) * IMG_W + (tilex + lx)) * 5;
  out[o + 0] = accr;
  out[o + 1] = accg;
  out[o + 2] = accb;
  out[o + 3] = accd;
  out[o + 4] = 1.0f - T;
}

extern "C" void kernel_launch(void* const* d_in, const int* in_sizes, int n_in,
                              void* d_out, int out_size, void* d_ws,
                              size_t ws_size, hipStream_t stream) {
  const float* pc = (const float*)d_in[0];
  const float* col = (const float*)d_in[1];
  const float* alp = (const float*)d_in[2];
  const float* con = (const float*)d_in[3];
  const float* q = (const float*)d_in[4];
  const float* t = (const float*)d_in[5];
  const float* K = (const float*)d_in[6];
  float* out = (float*)d_out;
  float* sorted = (float*)d_ws;  // 2048*12 floats

  gs_sortsetup<<<(NPTS * 32) / 256, 256, 0, stream>>>(pc, col, alp, con, q, t,
                                                      K, sorted);
  gs_raster<<<(IMG_H / TILE) * (IMG_W / TILE), 256, 0, stream>>>(sorted, out);
}

// Round 4
// 20.802 us; speedup vs baseline: 4.8910x; 1.0181x over previous
//
#include <hip/hip_runtime.h>
#include <math.h>

#define NPTS 2048
#define IMG_W 512
#define IMG_H 512
#define TILE 16
#define CAP 384      // survivor capacity (expected ~70 worst tile)
#define RSTRIDE 12   // w0=(ux,uy,A,B) w1=(C,a,depth,orig) w2=(r,g,b,0)

// ---------------------------------------------------------------------------
// Single fused kernel: one 256-thread block per 16x16 tile.
// 1) cull all 2048 unsorted points vs tile (projection recomputed on the fly)
// 2) ordered compaction of survivors (+ full records) into LDS
// 3) rank-sort survivors by (depth, orig) == reference stable argsort order
//    restricted to contributing points (culled points have alpha == 0 exactly)
// 4) front-to-back composite
// ---------------------------------------------------------------------------
__global__ __launch_bounds__(256) void gs_fused(
    const float* __restrict__ pc,   // (N,3)
    const float* __restrict__ col,  // (N,3)
    const float* __restrict__ alp,  // (N,)
    const float* __restrict__ con,  // (N,3)
    const float* __restrict__ q,    // (4,)
    const float* __restrict__ t,    // (3,)
    const float* __restrict__ K,    // (3,3)
    float* __restrict__ out) {
  __shared__ float s_pts[CAP * RSTRIDE];
  __shared__ float2 s_do[CAP];  // (depth, orig) sort keys
  __shared__ int s_cnt[32];     // [chunk][wave]

  int tid = threadIdx.x;
  int lane = tid & 63, wave = tid >> 6;
  int tilex = (blockIdx.x % (IMG_W / TILE)) * TILE;
  int tiley = (blockIdx.x / (IMG_W / TILE)) * TILE;
  int lx = tid % TILE, ly = tid / TILE;
  float px = tilex + lx + 0.5f, py = tiley + ly + 0.5f;
  float tx0 = tilex + 0.5f, tx1 = tilex + TILE - 0.5f;
  float ty0 = tiley + 0.5f, ty1 = tiley + TILE - 0.5f;

  // wave-uniform camera params (scalar loads)
  float qx = q[0], qy = q[1], qz = q[2], qw = q[3];
  float r00 = 1.f - 2.f * (qy * qy + qz * qz), r01 = 2.f * (qx * qy - qz * qw),
        r02 = 2.f * (qx * qz + qy * qw);
  float r10 = 2.f * (qx * qy + qz * qw), r11 = 1.f - 2.f * (qx * qx + qz * qz),
        r12 = 2.f * (qy * qz - qx * qw);
  float r20 = 2.f * (qx * qz - qy * qw), r21 = 2.f * (qy * qz + qx * qw),
        r22 = 1.f - 2.f * (qx * qx + qy * qy);
  float t0 = t[0], t1 = t[1], t2 = t[2];
  float fx = K[0], cx = K[2], fy = K[4], cy = K[5];

#define PROJ(i, ux, uy, Z)                              \
  float ux, uy, Z;                                      \
  {                                                     \
    float x = pc[3 * (i)], y = pc[3 * (i) + 1],         \
          z = pc[3 * (i) + 2];                          \
    Z = r20 * x + r21 * y + r22 * z + t2;               \
    float X = r00 * x + r01 * y + r02 * z + t0;         \
    float Y = r10 * x + r11 * y + r12 * z + t1;         \
    float inv = 1.0f / (Z + 1e-6f);                     \
    ux = (fx * X + cx * Z) * inv;                       \
    uy = (fy * Y + cy * Z) * inv;                       \
  }

  // ---- phase 1: cull ----
  unsigned pmask = 0;
  int miw[8];
#pragma unroll
  for (int c = 0; c < 8; c++) {
    int i = c * 256 + tid;
    PROJ(i, ux, uy, Z);
    float A = con[3 * i], B = con[3 * i + 1], C = con[3 * i + 2];
    float a = alp[i];
    float th = 2.0f * __logf(255.0f * a);  // keep iff min quadform <= th
    float absB = fabsf(B);
    float dxm = fmaxf(0.0f, fmaxf(tx0 - ux, ux - tx1));
    float dym = fmaxf(0.0f, fmaxf(ty0 - uy, uy - ty1));
    float bound =
        fmaxf(A - absB, 0.0f) * dxm * dxm + fmaxf(C - absB, 0.0f) * dym * dym;
    bool pred = bound <= th + 1e-3f;  // conservative slack
    unsigned long long m = __ballot(pred);
    miw[c] = __popcll(m & ((1ull << lane) - 1ull));
    if (lane == 0) s_cnt[c * 4 + wave] = (int)__popcll(m);
    pmask |= (unsigned)pred << c;
  }
  __syncthreads();

  // ---- prefix sums (broadcast LDS reads) ----
  int start[8], total;
  {
    int run = 0;
#pragma unroll
    for (int c = 0; c < 8; c++) {
      int s0 = s_cnt[c * 4 + 0], s1 = s_cnt[c * 4 + 1];
      int s2 = s_cnt[c * 4 + 2], s3 = s_cnt[c * 4 + 3];
      start[c] = run + (wave > 0 ? s0 : 0) + (wave > 1 ? s1 : 0) +
                 (wave > 2 ? s2 : 0);
      run += s0 + s1 + s2 + s3;
    }
    total = run;
  }

  float T = 1.0f, accr = 0.f, accg = 0.f, accb = 0.f, accd = 0.f;

#define COMPOSITE(w0, w1, w2)                                              \
  {                                                                        \
    float dx = px - w0.x, dy = py - w0.y;                                  \
    float pw =                                                             \
        -0.5f * (w0.z * dx * dx + 2.0f * w0.w * dx * dy + w1.x * dy * dy); \
    float gg = __expf(fminf(pw, 0.0f));                                    \
    float prod = gg * w1.y;                                                \
    if (prod >= (1.0f / 255.0f)) {                                         \
      float al = fminf(prod, 0.99f);                                       \
      float w = T * al;                                                    \
      accr += w * w2.x;                                                    \
      accg += w * w2.y;                                                    \
      accb += w * w2.z;                                                    \
      accd += w * w1.z;                                                    \
      T *= (1.0f - al);                                                    \
    }                                                                      \
  }

  if (total <= CAP) {
    // ---- phase 2: compact survivors (recompute full record) ----
#pragma unroll
    for (int c = 0; c < 8; c++) {
      if ((pmask >> c) & 1) {
        int i = c * 256 + tid;
        PROJ(i, ux, uy, Z);
        float a = alp[i];
        int slot = start[c] + miw[c];
        float4* d = (float4*)(s_pts + (size_t)slot * RSTRIDE);
        d[0] = {ux, uy, con[3 * i], con[3 * i + 1]};
        d[1] = {con[3 * i + 2], a, Z, (float)i};
        d[2] = {col[3 * i], col[3 * i + 1], col[3 * i + 2], 0.0f};
        s_do[slot] = {Z, (float)i};
      }
    }
    __syncthreads();

    // ---- phase 3: rank-sort survivors, in-place via register staging ----
    int k1 = tid, k2 = tid + 256;
    bool h1 = k1 < total, h2 = k2 < total;
    float2 d1 = h1 ? s_do[k1] : make_float2(1e30f, 1e30f);
    float2 d2 = h2 ? s_do[k2] : make_float2(1e30f, 1e30f);
    int r1 = 0, r2 = 0;
    for (int j = 0; j < total; j++) {
      float2 v = s_do[j];
      r1 += (v.x < d1.x) || (v.x == d1.x && v.y < d1.y);
      r2 += (v.x < d2.x) || (v.x == d2.x && v.y < d2.y);
    }
    float4 a1, b1, c1, a2, b2, c2;
    if (h1) {
      const float4* s = (const float4*)(s_pts + (size_t)k1 * RSTRIDE);
      a1 = s[0]; b1 = s[1]; c1 = s[2];
    }
    if (h2) {
      const float4* s = (const float4*)(s_pts + (size_t)k2 * RSTRIDE);
      a2 = s[0]; b2 = s[1]; c2 = s[2];
    }
    __syncthreads();
    if (h1) {
      float4* d = (float4*)(s_pts + (size_t)r1 * RSTRIDE);
      d[0] = a1; d[1] = b1; d[2] = c1;
    }
    if (h2) {
      float4* d = (float4*)(s_pts + (size_t)r2 * RSTRIDE);
      d[0] = a2; d[1] = b2; d[2] = c2;
    }
    __syncthreads();

    // ---- phase 4: composite front-to-back ----
    for (int k = 0; k < total; k++) {
      const float4* p4 = (const float4*)(s_pts + (size_t)k * RSTRIDE);
      float4 w0 = p4[0], w1 = p4[1], w2 = p4[2];
      COMPOSITE(w0, w1, w2);
      if (T < 1e-4f) break;
    }
  } else {
    // ---- exact fallback (never expected): block-wide select-min merge ----
    float dep[8];
#pragma unroll
    for (int c = 0; c < 8; c++) {
      int i = c * 256 + tid;
      float x = pc[3 * i], y = pc[3 * i + 1], z = pc[3 * i + 2];
      dep[c] = r20 * x + r21 * y + r22 * z + t2;
    }
    unsigned live = pmask;
    float* s_rd = s_pts;               // 256 floats
    int* s_ro = (int*)(s_pts + 256);   // 256 ints
    float* s_rec = s_pts + 512;        // 12-float winner record
    while (1) {
      float bd = 1e30f;
      int bo = 0x7fffffff;
#pragma unroll
      for (int c = 0; c < 8; c++) {
        if ((live >> c) & 1) {
          int o = c * 256 + tid;
          if (dep[c] < bd || (dep[c] == bd && o < bo)) { bd = dep[c]; bo = o; }
        }
      }
      s_rd[tid] = bd;
      s_ro[tid] = bo;
      __syncthreads();
      float wd = 1e30f;
      int wo = 0x7fffffff;
      for (int j = 0; j < 256; j++) {
        float d = s_rd[j];
        int o = s_ro[j];
        if (d < wd || (d == wd && o < wo)) { wd = d; wo = o; }
      }
      __syncthreads();
      if (wo == 0x7fffffff) break;
      if (tid == (wo & 255)) {
        int i = wo;
        PROJ(i, ux, uy, Z);
        float a = alp[i];
        float4* d = (float4*)s_rec;
        d[0] = {ux, uy, con[3 * i], con[3 * i + 1]};
        d[1] = {con[3 * i + 2], a, Z, (float)i};
        d[2] = {col[3 * i], col[3 * i + 1], col[3 * i + 2], 0.0f};
        live &= ~(1u << (wo >> 8));
      }
      __syncthreads();
      float4 w0 = ((float4*)s_rec)[0], w1 = ((float4*)s_rec)[1],
             w2 = ((float4*)s_rec)[2];
      COMPOSITE(w0, w1, w2);
    }
  }
#undef COMPOSITE
#undef PROJ

  int o = ((tiley + ly) * IMG_W + (tilex + lx)) * 5;
  out[o + 0] = accr;
  out[o + 1] = accg;
  out[o + 2] = accb;
  out[o + 3] = accd;
  out[o + 4] = 1.0f - T;
}

extern "C" void kernel_launch(void* const* d_in, const int* in_sizes, int n_in,
                              void* d_out, int out_size, void* d_ws,
                              size_t ws_size, hipStream_t stream) {
  const float* pc = (const float*)d_in[0];
  const float* col = (const float*)d_in[1];
  const float* alp = (const float*)d_in[2];
  const float* con = (const float*)d_in[3];
  const float* q = (const float*)d_in[4];
  const float* t = (const float*)d_in[5];
  const float* K = (const float*)d_in[6];
  float* out = (float*)d_out;

  gs_fused<<<(IMG_H / TILE) * (IMG_W / TILE), 256, 0, stream>>>(
      pc, col, alp, con, q, t, K, out);
}